// Round 3
// baseline (698.628 us; speedup 1.0000x reference)
//
#include <hip/hip_runtime.h>

#define T 2048
#define H 2048
#define E 8
#define KTOP 2
#define F 1408
#define FS 2816
#define NE 10            // 8 routed + 2 halves of the shared expert
#define NSLOT 8192       // T*KTOP routed slots + 2*T shared slots

typedef __attribute__((ext_vector_type(8))) short short8;
typedef __attribute__((ext_vector_type(4))) float f32x4;

__device__ __forceinline__ unsigned short f2bf(float f) {
  unsigned int u = __float_as_uint(f);
  u += 0x7fffu + ((u >> 16) & 1u);   // RNE
  return (unsigned short)(u >> 16);
}

__device__ __forceinline__ void load_lds16(const void* g, void* l) {
  __builtin_amdgcn_global_load_lds((__attribute__((address_space(1))) const unsigned int*)g,
                                   (__attribute__((address_space(3))) unsigned int*)l, 16, 0, 0);
}

// ---------------- conversion kernels (fp32 -> bf16, packed layouts) ----------------

__global__ __launch_bounds__(256) void conv_x(const float* __restrict__ x,
                                              unsigned short* __restrict__ xb) {
  const int total4 = T * H / 4;
  for (int i = blockIdx.x * 256 + threadIdx.x; i < total4; i += gridDim.x * 256) {
    float4 v = ((const float4*)x)[i];
    ushort4 o; o.x = f2bf(v.x); o.y = f2bf(v.y); o.z = f2bf(v.z); o.w = f2bf(v.w);
    ((ushort4*)xb)[i] = o;
  }
}

// wgu layout: [NE][2][F][H]  (m=0 gate, m=1 up)
__global__ __launch_bounds__(256) void conv_wgu(const float* __restrict__ wg,
                                                const float* __restrict__ wu,
                                                const float* __restrict__ swg,
                                                const float* __restrict__ swu,
                                                unsigned short* __restrict__ dst) {
  const int total4 = NE * 2 * F * H / 4;
  for (int i = blockIdx.x * 256 + threadIdx.x; i < total4; i += gridDim.x * 256) {
    int o = i * 4;
    int e = o / (2 * F * H);
    int r = o - e * (2 * F * H);
    int m = r / (F * H);
    int fh = r - m * (F * H);
    const float* src;
    if (e < 8) {
      src = (m ? wu : wg) + (size_t)e * (F * H) + fh;
    } else {
      int f = fh / H, h = fh - f * H;
      src = (m ? swu : swg) + ((size_t)((e - 8) * F + f)) * H + h;
    }
    float4 v = *(const float4*)src;
    ushort4 ov; ov.x = f2bf(v.x); ov.y = f2bf(v.y); ov.z = f2bf(v.z); ov.w = f2bf(v.w);
    *(ushort4*)(dst + o) = ov;
  }
}

// wd layout: [NE][H][F]
__global__ __launch_bounds__(256) void conv_wd(const float* __restrict__ wdn,
                                               const float* __restrict__ swd,
                                               unsigned short* __restrict__ dst) {
  const int total4 = NE * H * F / 4;
  for (int i = blockIdx.x * 256 + threadIdx.x; i < total4; i += gridDim.x * 256) {
    int o = i * 4;
    int e = o / (H * F);
    int hf = o - e * (H * F);
    const float* src;
    if (e < 8) {
      src = wdn + (size_t)e * (H * F) + hf;
    } else {
      int h = hf / F, f = hf - h * F;
      src = swd + (size_t)h * FS + (e - 8) * F + f;
    }
    float4 v = *(const float4*)src;
    ushort4 ov; ov.x = f2bf(v.x); ov.y = f2bf(v.y); ov.z = f2bf(v.z); ov.w = f2bf(v.w);
    *(ushort4*)(dst + o) = ov;
  }
}

// ---------------- gating: fp32 logits, softmax, top-2, counts ----------------

__global__ __launch_bounds__(256) void gate_topk(const float* __restrict__ x,
                                                 const float* __restrict__ gw,
                                                 int* __restrict__ tidx,
                                                 float* __restrict__ tw,
                                                 int* __restrict__ counts) {
  const int wv = threadIdx.x >> 6, lane = threadIdx.x & 63;
  const int t = blockIdx.x * 4 + wv;
  float acc[E];
#pragma unroll
  for (int e = 0; e < E; ++e) acc[e] = 0.f;
  const float4* xr = (const float4*)(x + (size_t)t * H);
#pragma unroll
  for (int it = 0; it < H / 4 / 64; ++it) {
    float4 xv = xr[lane + it * 64];
#pragma unroll
    for (int e = 0; e < E; ++e) {
      float4 wvv = ((const float4*)(gw + (size_t)e * H))[lane + it * 64];
      acc[e] += xv.x * wvv.x + xv.y * wvv.y + xv.z * wvv.z + xv.w * wvv.w;
    }
  }
#pragma unroll
  for (int off = 32; off >= 1; off >>= 1) {
#pragma unroll
    for (int e = 0; e < E; ++e) acc[e] += __shfl_down(acc[e], off);
  }
  if (lane == 0) {
    float mx = acc[0];
#pragma unroll
    for (int e = 1; e < E; ++e) mx = fmaxf(mx, acc[e]);
    float s[E]; float sum = 0.f;
#pragma unroll
    for (int e = 0; e < E; ++e) { s[e] = expf(acc[e] - mx); sum += s[e]; }
    float inv = 1.f / sum;
#pragma unroll
    for (int e = 0; e < E; ++e) s[e] *= inv;
    int i0 = 0; float b0 = s[0];
#pragma unroll
    for (int e = 1; e < E; ++e) if (s[e] > b0) { b0 = s[e]; i0 = e; }
    int i1 = -1; float b1 = -1.f;
#pragma unroll
    for (int e = 0; e < E; ++e) if (e != i0 && s[e] > b1) { b1 = s[e]; i1 = e; }
    float dn = 1.f / (b0 + b1 + 1e-20f);
    tidx[t * 2] = i0; tidx[t * 2 + 1] = i1;
    tw[t * 2] = b0 * dn; tw[t * 2 + 1] = b1 * dn;
    atomicAdd(&counts[i0], 1);
    atomicAdd(&counts[i1], 1);
  }
}

__global__ void prefix_k(const int* __restrict__ counts, int* __restrict__ mbase,
                         int* __restrict__ mcount, int* __restrict__ cursors) {
  if (threadIdx.x == 0) {
    int cum = 0;
    for (int e = 0; e < 8; ++e) { mbase[e] = cum; mcount[e] = counts[e]; cum += counts[e]; }
    mbase[8] = cum;     mcount[8] = T;   // cum == 4096 (every token picks exactly 2)
    mbase[9] = cum + T; mcount[9] = T;
  }
  if (threadIdx.x < 16) cursors[threadIdx.x] = 0;
}

__global__ __launch_bounds__(256) void scatter_k(const int* __restrict__ tidx,
                                                 const float* __restrict__ tw,
                                                 const int* __restrict__ mbase,
                                                 int* __restrict__ cursors,
                                                 int* __restrict__ slot_token,
                                                 float* __restrict__ slot_w) {
  const int t = blockIdx.x * 256 + threadIdx.x;
#pragma unroll
  for (int k = 0; k < 2; ++k) {
    int e = tidx[t * 2 + k];
    int pos = atomicAdd(&cursors[e], 1);
    int slot = mbase[e] + pos;
    slot_token[slot] = t;
    slot_w[slot] = tw[t * 2 + k];
  }
  slot_token[4096 + t] = t; slot_w[4096 + t] = 1.f;
  slot_token[6144 + t] = t; slot_w[6144 + t] = 1.f;
}

// ---------------- grouped GEMMs (m97-style 128x128x64, global_load_lds w16) ----------------

#define BM 128
#define BN 128
#define BK 64

// GEMM1: [slots x H] @ [F x H]^T for gate AND up, epilogue silu(g)*u -> gbuf bf16
__global__ __launch_bounds__(256, 2)
void gemm_gateup(const unsigned short* __restrict__ xb, const unsigned short* __restrict__ wgu,
                 const int* __restrict__ slot_token,
                 const int* __restrict__ mbase, const int* __restrict__ mcount,
                 unsigned short* __restrict__ gbuf) {
  const int nt = blockIdx.x;        // 0..10  (F/BN)
  const int e = blockIdx.y >> 4;    // 0..9
  const int mt = blockIdx.y & 15;
  const int cnt = mcount[e];
  if (mt * BM >= cnt) return;
  const int base = mbase[e];

  __shared__ unsigned short lA[BM * BK];
  __shared__ unsigned short lBg[BN * BK];
  __shared__ unsigned short lBu[BN * BK];

  const int tid = threadIdx.x;
  const int wid = tid >> 6;
  const int lane = tid & 63;
  const int rql = tid >> 3;         // 0..31 : row within a 32-row j-group
  const int cq = (tid & 7) * 8;     // element offset within a 64-elem K slab

  // A: gathered token rows (tokens constant over K loop)
  const unsigned short* aP[4];
#pragma unroll
  for (int j = 0; j < 4; ++j) {
    int m = mt * BM + j * 32 + rql;
    int mm = m < cnt ? m : cnt - 1;
    int tok = slot_token[base + mm];
    aP[j] = xb + (size_t)tok * H + cq;
  }
  const unsigned short* bgP = wgu + (size_t)e * (2 * F * H) + (size_t)(nt * BN + rql) * H + cq;
  const unsigned short* buP = bgP + (size_t)F * H;

  f32x4 accg[4][4], accu[4][4];
  const f32x4 z4 = {0.f, 0.f, 0.f, 0.f};
#pragma unroll
  for (int i = 0; i < 4; ++i)
#pragma unroll
    for (int j = 0; j < 4; ++j) { accg[i][j] = z4; accu[i][j] = z4; }

  const int wm = (wid >> 1) * 64;
  const int wn = (wid & 1) * 64;
  const int fr = lane & 15;
  const int kq = (lane >> 4) * 8;

  for (int kt = 0; kt < H; kt += BK) {
#pragma unroll
    for (int j = 0; j < 4; ++j) {
      int lo = (j * 256 + wid * 64) * 8;
      load_lds16(aP[j] + kt, &lA[lo]);
      load_lds16(bgP + j * 32 * H + kt, &lBg[lo]);
      load_lds16(buP + j * 32 * H + kt, &lBu[lo]);
    }
    __syncthreads();   // vmcnt drain + barrier
#pragma unroll
    for (int ks = 0; ks < 2; ++ks) {
      short8 af[4], bg[4], bu[4];
      const int ko = ks * 32 + kq;
#pragma unroll
      for (int i = 0; i < 4; ++i) af[i] = *(const short8*)&lA[(wm + i * 16 + fr) * BK + ko];
#pragma unroll
      for (int i = 0; i < 4; ++i) bg[i] = *(const short8*)&lBg[(wn + i * 16 + fr) * BK + ko];
#pragma unroll
      for (int i = 0; i < 4; ++i) bu[i] = *(const short8*)&lBu[(wn + i * 16 + fr) * BK + ko];
#pragma unroll
      for (int i = 0; i < 4; ++i)
#pragma unroll
        for (int j = 0; j < 4; ++j) {
          accg[i][j] = __builtin_amdgcn_mfma_f32_16x16x32_bf16(af[i], bg[j], accg[i][j], 0, 0, 0);
          accu[i][j] = __builtin_amdgcn_mfma_f32_16x16x32_bf16(af[i], bu[j], accu[i][j], 0, 0, 0);
        }
    }
    __syncthreads();
  }

  // epilogue: g = silu(zg) * zu, store bf16
  const int r0 = (lane >> 4) * 4;
#pragma unroll
  for (int i = 0; i < 4; ++i) {
#pragma unroll
    for (int r = 0; r < 4; ++r) {
      int m = mt * BM + wm + i * 16 + r0 + r;
      if (m < cnt) {
        size_t rowoff = (size_t)(base + m) * F + nt * BN + wn + fr;
#pragma unroll
        for (int j = 0; j < 4; ++j) {
          float zg = accg[i][j][r], zu = accu[i][j][r];
          float gv = zu * zg / (1.f + __expf(-zg));
          gbuf[rowoff + j * 16] = f2bf(gv);
        }
      }
    }
  }
}

// GEMM2: [slots x F] @ [H x F]^T, epilogue atomicAdd(out[token], w * acc)
__global__ __launch_bounds__(256, 2)
void gemm_down(const unsigned short* __restrict__ gbuf, const unsigned short* __restrict__ wd,
               const int* __restrict__ slot_token, const float* __restrict__ slot_w,
               const int* __restrict__ mbase, const int* __restrict__ mcount,
               float* __restrict__ out) {
  const int nt = blockIdx.x;        // 0..15 (H/BN)
  const int e = blockIdx.y >> 4;
  const int mt = blockIdx.y & 15;
  const int cnt = mcount[e];
  if (mt * BM >= cnt) return;
  const int base = mbase[e];

  __shared__ unsigned short lA[BM * BK];
  __shared__ unsigned short lB[BN * BK];

  const int tid = threadIdx.x;
  const int wid = tid >> 6;
  const int lane = tid & 63;
  const int rql = tid >> 3;
  const int cq = (tid & 7) * 8;

  const unsigned short* aP[4];
#pragma unroll
  for (int j = 0; j < 4; ++j) {
    int m = mt * BM + j * 32 + rql;
    int mm = m < cnt ? m : cnt - 1;
    aP[j] = gbuf + (size_t)(base + mm) * F + cq;
  }
  const unsigned short* bP = wd + (size_t)e * (H * F) + (size_t)(nt * BN + rql) * F + cq;

  f32x4 acc[4][4];
  const f32x4 z4 = {0.f, 0.f, 0.f, 0.f};
#pragma unroll
  for (int i = 0; i < 4; ++i)
#pragma unroll
    for (int j = 0; j < 4; ++j) acc[i][j] = z4;

  const int wm = (wid >> 1) * 64;
  const int wn = (wid & 1) * 64;
  const int fr = lane & 15;
  const int kq = (lane >> 4) * 8;

  for (int kt = 0; kt < F; kt += BK) {   // 22 iters
#pragma unroll
    for (int j = 0; j < 4; ++j) {
      int lo = (j * 256 + wid * 64) * 8;
      load_lds16(aP[j] + kt, &lA[lo]);
      load_lds16(bP + j * 32 * F + kt, &lB[lo]);
    }
    __syncthreads();
#pragma unroll
    for (int ks = 0; ks < 2; ++ks) {
      short8 af[4], bf[4];
      const int ko = ks * 32 + kq;
#pragma unroll
      for (int i = 0; i < 4; ++i) af[i] = *(const short8*)&lA[(wm + i * 16 + fr) * BK + ko];
#pragma unroll
      for (int i = 0; i < 4; ++i) bf[i] = *(const short8*)&lB[(wn + i * 16 + fr) * BK + ko];
#pragma unroll
      for (int i = 0; i < 4; ++i)
#pragma unroll
        for (int j = 0; j < 4; ++j)
          acc[i][j] = __builtin_amdgcn_mfma_f32_16x16x32_bf16(af[i], bf[j], acc[i][j], 0, 0, 0);
    }
    __syncthreads();
  }

  const int r0 = (lane >> 4) * 4;
#pragma unroll
  for (int i = 0; i < 4; ++i) {
#pragma unroll
    for (int r = 0; r < 4; ++r) {
      int m = mt * BM + wm + i * 16 + r0 + r;
      if (m < cnt) {
        int slot = base + m;
        int tok = slot_token[slot];
        float w = slot_w[slot];
        float* orow = out + (size_t)tok * H + nt * BN + wn + fr;
#pragma unroll
        for (int j = 0; j < 4; ++j) atomicAdd(&orow[j * 16], w * acc[i][j][r]);
      }
    }
  }
}

// ---------------- launch ----------------

extern "C" void kernel_launch(void* const* d_in, const int* in_sizes, int n_in,
                              void* d_out, int out_size, void* d_ws, size_t ws_size,
                              hipStream_t stream) {
  const float* x       = (const float*)d_in[0];
  const float* gw      = (const float*)d_in[1];
  const float* w_gate  = (const float*)d_in[2];
  const float* w_up    = (const float*)d_in[3];
  const float* w_down  = (const float*)d_in[4];
  const float* sw_gate = (const float*)d_in[5];
  const float* sw_up   = (const float*)d_in[6];
  const float* sw_down = (const float*)d_in[7];
  float* out = (float*)d_out;

  char* p = (char*)d_ws;
  auto alloc = [&](size_t bytes) { char* r = p; p += (bytes + 255) & ~(size_t)255; return r; };
  int*   counts     = (int*)alloc(64);
  int*   cursors    = (int*)alloc(64);
  int*   mbase      = (int*)alloc(64);
  int*   mcount     = (int*)alloc(64);
  int*   tidx       = (int*)alloc((size_t)T * KTOP * 4);
  float* tw         = (float*)alloc((size_t)T * KTOP * 4);
  int*   slot_token = (int*)alloc((size_t)NSLOT * 4);
  float* slot_w     = (float*)alloc((size_t)NSLOT * 4);
  unsigned short* xb   = (unsigned short*)alloc((size_t)T * H * 2);
  unsigned short* gbuf = (unsigned short*)alloc((size_t)NSLOT * F * 2);
  unsigned short* wgu  = (unsigned short*)alloc((size_t)NE * 2 * F * H * 2);
  unsigned short* wd   = (unsigned short*)alloc((size_t)NE * H * F * 2);

  hipMemsetAsync(counts, 0, 64, stream);
  hipMemsetAsync(out, 0, (size_t)out_size * 4, stream);

  conv_x<<<1024, 256, 0, stream>>>(x, xb);
  conv_wgu<<<2048, 256, 0, stream>>>(w_gate, w_up, sw_gate, sw_up, wgu);
  conv_wd<<<2048, 256, 0, stream>>>(w_down, sw_down, wd);
  gate_topk<<<T / 4, 256, 0, stream>>>(x, gw, tidx, tw, counts);
  prefix_k<<<1, 64, 0, stream>>>(counts, mbase, mcount, cursors);
  scatter_k<<<T / 256, 256, 0, stream>>>(tidx, tw, mbase, cursors, slot_token, slot_w);
  gemm_gateup<<<dim3(F / BN, NE * 16), 256, 0, stream>>>(xb, wgu, slot_token, mbase, mcount, gbuf);
  gemm_down<<<dim3(H / BN, NE * 16), 256, 0, stream>>>(gbuf, wd, slot_token, slot_w, mbase, mcount, out);
}